// Round 7
// baseline (307.285 us; speedup 1.0000x reference)
//
#include <hip/hip_runtime.h>
#include <math.h>

typedef __attribute__((ext_vector_type(8))) short  short8;   // 8 bf16 (4 VGPRs) - MFMA A/B frag
typedef __attribute__((ext_vector_type(4))) float  floatx4;  // MFMA C/D frag
typedef __attribute__((ext_vector_type(2))) float  float2v;  // packed pair (v_pk_add_f32)
typedef __attribute__((ext_vector_type(4))) unsigned int uintx4; // 16B vector load

#define NLOCI 8
#define VOCAB 512
#define DDIM  256
#define HID   512
#define NSAMP (8192 * 16)

__device__ __forceinline__ float bitsf(unsigned int u) {
    union { unsigned int u; float f; } c; c.u = u; return c.f;
}
__device__ __forceinline__ unsigned short f2bf(float f) {  // RNE (used in prep, cold path)
    union { float f; unsigned int u; } c; c.f = f;
    unsigned int u = c.u;
    return (unsigned short)((u + 0x7FFFu + ((u >> 16) & 1u)) >> 16);
}
__device__ __forceinline__ unsigned short f2bf_fast(float f) {  // round-half-up, 2 ops
    union { float f; unsigned int u; } c; c.f = f;
    return (unsigned short)((c.u + 0x8000u) >> 16);
}
// tanh-form GELU via exp2+rcp; |diff vs erf-GELU| ~3e-4 << threshold.
__device__ __forceinline__ float gelu_fast(float x) {
    float t = x * x;
    float y = x * __builtin_fmaf(0.035677408f, t, 0.79788456f);
    float e = __builtin_amdgcn_exp2f(y * 2.8853901f);
    float r = __builtin_amdgcn_rcpf(e + 1.0f);
    return x - x * r;
}
// async 16B/lane global->LDS DMA (lane i lands at lds_base + i*16)
__device__ __forceinline__ void async_copy16(const void* g, void* l) {
    __builtin_amdgcn_global_load_lds(
        (const __attribute__((address_space(1))) unsigned int*)g,
        (__attribute__((address_space(3))) unsigned int*)l, 16, 0, 0);
}

// sum 8 loci (packed bf16 pairs) -> GELU -> bf16 afrag
__device__ __forceinline__ short8 sum_gelu(const uintx4* g) {
    short8 afrag;
#pragma unroll
    for (int j = 0; j < 4; ++j) {
        float2v u0 = (float2v){bitsf(g[0][j] << 16), bitsf(g[0][j] & 0xFFFF0000u)};
        float2v u1 = (float2v){bitsf(g[1][j] << 16), bitsf(g[1][j] & 0xFFFF0000u)};
        float2v u2 = (float2v){bitsf(g[2][j] << 16), bitsf(g[2][j] & 0xFFFF0000u)};
        float2v u3 = (float2v){bitsf(g[3][j] << 16), bitsf(g[3][j] & 0xFFFF0000u)};
        float2v u4 = (float2v){bitsf(g[4][j] << 16), bitsf(g[4][j] & 0xFFFF0000u)};
        float2v u5 = (float2v){bitsf(g[5][j] << 16), bitsf(g[5][j] & 0xFFFF0000u)};
        float2v u6 = (float2v){bitsf(g[6][j] << 16), bitsf(g[6][j] & 0xFFFF0000u)};
        float2v u7 = (float2v){bitsf(g[7][j] << 16), bitsf(g[7][j] & 0xFFFF0000u)};
        float2v sj = ((u0 + u1) + (u2 + u3)) + ((u4 + u5) + (u6 + u7));
        afrag[2 * j]     = (short)f2bf_fast(gelu_fast(sj[0]));
        afrag[2 * j + 1] = (short)f2bf_fast(gelu_fast(sj[1]));
    }
    return afrag;
}

// ---------------------------------------------------------------------------
// Kernel 1 (merged): blocks [0,512): Tp[l] = tables[l] @ W1-slice, bf16,
// b1 folded into locus 0.  blocks [512,544): W2 transpose+cvt -> W2t.
// XOR-swizzled LDS tiles (32 chunks of 16B per row):
//   element (row, k) lives at row*256 + ((k>>3) ^ (row&31))*8 + (k&7)  [shorts]
// ---------------------------------------------------------------------------
__global__ __launch_bounds__(256) void k_prep(
    const float* __restrict__ tables,   // [8][512][256] f32
    const float* __restrict__ W1,       // [2048][512] f32
    const float* __restrict__ b1,       // [512] f32
    const float* __restrict__ W2,       // [512][256] f32
    unsigned short* __restrict__ Tp,    // [8][512][512] bf16
    unsigned short* __restrict__ W2t)   // [256][512] bf16
{
    __shared__ unsigned short a_lds[64 * 256];   // 32 KB, swizzled
    __shared__ unsigned short bt_lds[64 * 256];  // 32 KB, swizzled (bt[n][k])

    const int t = threadIdx.x;

    if (blockIdx.x >= 512) {
        // ---- W2 transpose+cvt: out[c][r] = bf16(in[r][c]), in [512][256] f32
        const int bid = blockIdx.x - 512;
        const int r0 = (bid & 7) * 64;   // over HID=512 rows
        const int c0 = (bid >> 3) * 64;  // over DDIM=256 cols
        float* tile = (float*)a_lds;     // 64*65*4 = 16.6 KB <= 32 KB
#pragma unroll
        for (int i = 0; i < 16; ++i) {
            int flat = i * 256 + t;
            int rr = flat >> 6, cc = flat & 63;
            tile[rr * 65 + cc] = W2[(r0 + rr) * DDIM + c0 + cc];
        }
        __syncthreads();
#pragma unroll
        for (int i = 0; i < 8; ++i) {
            int flat = i * 256 + t;
            int cc = flat >> 5, rp = (flat & 31) * 2;
            ushort2 v;
            v.x = f2bf(tile[rp * 65 + cc]);
            v.y = f2bf(tile[(rp + 1) * 65 + cc]);
            *(ushort2*)(W2t + (c0 + cc) * HID + r0 + rp) = v;
        }
        return;
    }

    const int l  = blockIdx.x >> 6;
    const int v0 = ((blockIdx.x >> 3) & 7) * 64;
    const int n0 = (blockIdx.x & 7) * 64;

    // ---- stage A (tables tile): float4 coalesced loads, conflict-free writes
    {
        const float* asrc = tables + (l * 512 + v0) * 256;
#pragma unroll
        for (int i = 0; i < 16; ++i) {
            int flat = i * 1024 + t * 4;
            int row = flat >> 8, k = flat & 255;
            float4 v = *(const float4*)(asrc + flat);
            ushort4 pk4;
            pk4.x = f2bf(v.x); pk4.y = f2bf(v.y); pk4.z = f2bf(v.z); pk4.w = f2bf(v.w);
            int chunkX = (k >> 3) ^ (row & 31);
            *(ushort4*)(a_lds + row * 256 + chunkX * 8 + (k & 7)) = pk4;
        }
    }
    // ---- stage B^T: bt[n][k] = bf16(W1[l*256+k][n0+n])
    {
        const int n = t & 63;
        const int kq = (t >> 6) * 64;
        const float* bsrc = W1 + (l * 256) * 512 + n0 + n;
#pragma unroll
        for (int i = 0; i < 8; ++i) {
            int k0 = kq + i * 8;
            short8 pk8;
#pragma unroll
            for (int j = 0; j < 8; ++j)
                pk8[j] = (short)f2bf(bsrc[(k0 + j) * 512]);
            int chunkX = (k0 >> 3) ^ (n & 31);
            *(short8*)(bt_lds + n * 256 + chunkX * 8) = pk8;
        }
    }
    __syncthreads();

    const int wave = t >> 6, lane = t & 63;
    const int p = lane & 15, q = lane >> 4;
    const int arow = wave * 16 + p;

    floatx4 acc[4];
#pragma unroll
    for (int nt = 0; nt < 4; ++nt) acc[nt] = (floatx4){0.f, 0.f, 0.f, 0.f};

#pragma unroll
    for (int kc = 0; kc < 8; ++kc) {
        int cq = kc * 4 + q;
        short8 afrag = *(const short8*)(a_lds + arow * 256 + (cq ^ (arow & 31)) * 8);
#pragma unroll
        for (int nt = 0; nt < 4; ++nt) {
            int brow = nt * 16 + p;
            short8 bfrag = *(const short8*)(bt_lds + brow * 256 + (cq ^ (brow & 31)) * 8);
            acc[nt] = __builtin_amdgcn_mfma_f32_16x16x32_bf16(afrag, bfrag, acc[nt], 0, 0, 0);
        }
    }

    // D: row(M=vocab) = q*4 + r, col(N) = nt*16 + p; fold b1 at l==0
#pragma unroll
    for (int nt = 0; nt < 4; ++nt) {
        int col = n0 + nt * 16 + p;
        float badd = (l == 0) ? b1[col] : 0.0f;
#pragma unroll
        for (int r = 0; r < 4; ++r) {
            int row = v0 + wave * 16 + q * 4 + r;
            Tp[(l * 512 + row) * 512 + col] = f2bf(acc[nt][r] + badd);
        }
    }
}

// ---------------------------------------------------------------------------
// Kernel 2: fused gather + GELU + (h @ W2 + b2)
// (identical to round-6 source — that round died to a container-infra
//  failure, not the kernel; vmcnt/barrier/WAR/OOB audit in journal)
//  (a) SINGLE 32-reg gather buffer + __launch_bounds__(256,4) -> 4 blocks/CU.
//      First half of each lane's 128B line prefetched 1 full tile ahead;
//      second half loaded JIT (same line -> L1/L2 hit, covered by barrier +
//      16 MFMAs). Arch live ~56-60 <= 64 (r0 precedent: 64 arch + 64 acc
//      fits at (256,4) with a 32-reg gather buffer).
//  (b) ror1 chunk->slot permutation kills r5's 8.4M LDS bank conflicts:
//      slot j at row n holds logical chunk c where j = ror1(c) ^ (n&7).
//      Read slot = ror1(2q+kc)^(p&7) = (q+4kc)^(p&7)  <- the r1 pattern
//      measured at ZERO conflicts. DMA source chunk = rol1(j ^ (drow&7)).
//      Same k-partition as r5 -> identical math/absmax.
//   per tile kb:
//     lgkm0; barrier1
//     DMA(kb) x8                      [out: gbuf(kb,h0) 8 + DMA 8]
//     vmcnt(8): gbuf h0 arrived       (DMA still flying)
//     afrag0 = sum_gelu(gbuf)
//     issue gbuf <- (kb,h1) x8 (JIT, same lines)
//     vmcnt(8): DMA drained           (JIT flying)
//     barrier2
//     MFMA kc0 x16 (slot q^p7)
//     vmcnt(0): JIT arrived
//     afrag1 = sum_gelu(gbuf)
//     issue gbuf <- (kb+1,h0) x8      (1-tile prefetch, crosses barriers)
//     MFMA kc1 x16 (slot (4+q)^p7)
// ---------------------------------------------------------------------------
__global__ __launch_bounds__(256, 4) void k_main(
    const int* __restrict__ hap,              // [131072][8] int32
    const unsigned short* __restrict__ Tp,    // [8][512][512] bf16 (b1 folded)
    const unsigned short* __restrict__ W2t,   // [256][512] bf16
    const float* __restrict__ b2,             // [256] f32
    float* __restrict__ out)                  // [131072][256] f32
{
    // w2 tile: [n=256][slot=8 of 16B]; slot j at row n holds chunk rol1(j^(n&7))
    __shared__ unsigned short w2_lds[256 * 64];  // 32 KB exactly

    const int t = threadIdx.x;
    const int wave = t >> 6, lane = t & 63;
    const int p = lane & 15, q = lane >> 4;
    const int m_base = blockIdx.x * 64 + wave * 16;

    // ---- 32-bit byte offsets of the 8 gathered Tp rows (q*32 folded: each
    // lane owns a contiguous 32B span = both half-slices of each 128B tile)
    unsigned int goff[8];
    {
        const uintx4* hp = (const uintx4*)(hap + (m_base + p) * 8);
        uintx4 h0 = hp[0], h1 = hp[1];
#pragma unroll
        for (int l = 0; l < 4; ++l) {
            goff[l]     = (unsigned)(l)     * 524288u + (h0[l] & 511u) * 1024u + (unsigned)(q * 32);
            goff[l + 4] = (unsigned)(l + 4) * 524288u + (h1[l] & 511u) * 1024u + (unsigned)(q * 32);
        }
    }
    const char* Tpc = (const char*)Tp;

    // ---- DMA lane mapping for W2 staging: dest slot j=(lane&7) at row drow;
    // source chunk c = rol1(j ^ (drow&7))   (3-bit rotate-left)
    const int drow = lane >> 3;
    const int jx = (lane & 7) ^ (drow & 7);
    const int c_src = (((jx << 1) | (jx >> 2)) & 7);
    const unsigned short* wsrc = W2t + (wave * 64 + drow) * 512 + c_src * 8;
    const int p7 = p & 7;

    floatx4 acc[16];
#pragma unroll
    for (int nt = 0; nt < 16; ++nt) acc[nt] = (floatx4){0.f, 0.f, 0.f, 0.f};

    // prologue: issue tile-0 first-half gathers
    uintx4 gbuf[8];
#pragma unroll
    for (int l = 0; l < 8; ++l)
        gbuf[l] = *(const uintx4*)(Tpc + goff[l]);
    __builtin_amdgcn_sched_barrier(0);

#pragma unroll
    for (int kb = 0; kb < 8; ++kb) {
        // barrier 1: all waves done reading tile kb-1 from LDS
        asm volatile("s_waitcnt lgkmcnt(0)" ::: "memory");
        __builtin_amdgcn_s_barrier();
        __builtin_amdgcn_sched_barrier(0);
#pragma unroll
        for (int i = 0; i < 8; ++i)
            async_copy16(wsrc + kb * 64 + i * 8 * 512,
                         w2_lds + (wave * 64 + i * 8) * 64);
        __builtin_amdgcn_sched_barrier(0);

        // first half (issued 1 tile ago) arrived; DMA(8) still flying
        asm volatile("s_waitcnt vmcnt(8)" ::: "memory");
        short8 afrag0 = sum_gelu(gbuf);
        __builtin_amdgcn_sched_barrier(0);

        // JIT second half of the SAME 128B lines (L1/L2-hit expected)
#pragma unroll
        for (int l = 0; l < 8; ++l)
            gbuf[l] = *(const uintx4*)(Tpc + goff[l] + kb * 128 + 16);
        __builtin_amdgcn_sched_barrier(0);

        // barrier 2: own DMA drained (older than JIT); 8 JIT loads stay flying
        asm volatile("s_waitcnt vmcnt(8)" ::: "memory");
        __builtin_amdgcn_s_barrier();
        __builtin_amdgcn_sched_barrier(0);

        // MFMA slice kc=0: slot = (0*4+q)^p7  (ror1'd layout -> r1's
        // conflict-free bank pattern)
        {
            const unsigned short* b0 = w2_lds + p * 64 + ((q ^ p7) * 8);
            __builtin_amdgcn_s_setprio(1);
#pragma unroll
            for (int nt = 0; nt < 16; ++nt) {
                short8 bfrag = *(const short8*)(b0 + nt * 1024);
                acc[nt] = __builtin_amdgcn_mfma_f32_16x16x32_bf16(afrag0, bfrag, acc[nt], 0, 0, 0);
            }
            __builtin_amdgcn_s_setprio(0);
        }

        // second half ready
        asm volatile("s_waitcnt vmcnt(0)" ::: "memory");
        short8 afrag1 = sum_gelu(gbuf);
        __builtin_amdgcn_sched_barrier(0);

        // 1-tile-ahead prefetch of next first half (crosses both barriers)
        if (kb < 7) {
#pragma unroll
            for (int l = 0; l < 8; ++l)
                gbuf[l] = *(const uintx4*)(Tpc + goff[l] + (kb + 1) * 128);
            __builtin_amdgcn_sched_barrier(0);
        }

        // MFMA slice kc=1: slot = (4+q)^p7
        {
            const unsigned short* b1p = w2_lds + p * 64 + (((4 + q) ^ p7) * 8);
            __builtin_amdgcn_s_setprio(1);
#pragma unroll
            for (int nt = 0; nt < 16; ++nt) {
                short8 bfrag = *(const short8*)(b1p + nt * 1024);
                acc[nt] = __builtin_amdgcn_mfma_f32_16x16x32_bf16(afrag1, bfrag, acc[nt], 0, 0, 0);
            }
            __builtin_amdgcn_s_setprio(0);
        }
    }

    // epilogue: D row(M=sample) = q*4+r, col(N) = nt*16+p; add b2, NT store f32
#pragma unroll
    for (int nt = 0; nt < 16; ++nt) {
        int n = nt * 16 + p;
        float b2v = b2[n];
#pragma unroll
        for (int r = 0; r < 4; ++r) {
            int m = m_base + q * 4 + r;
            __builtin_nontemporal_store(acc[nt][r] + b2v, out + m * 256 + n);
        }
    }
}

// ---------------------------------------------------------------------------
extern "C" void kernel_launch(void* const* d_in, const int* in_sizes, int n_in,
                              void* d_out, int out_size, void* d_ws, size_t ws_size,
                              hipStream_t stream) {
    const int*   hap    = (const int*)d_in[0];
    const float* tables = (const float*)d_in[1];
    const float* W1     = (const float*)d_in[2];
    const float* b1     = (const float*)d_in[3];
    const float* W2     = (const float*)d_in[4];
    const float* b2     = (const float*)d_in[5];
    float*       outp   = (float*)d_out;

    unsigned short* Tp  = (unsigned short*)d_ws;                        // 4 MB bf16
    unsigned short* W2t = (unsigned short*)d_ws + NLOCI * VOCAB * HID;  // 256 KB

    k_prep<<<dim3(544), dim3(256), 0, stream>>>(tables, W1, b1, W2, Tp, W2t);
    k_main<<<dim3(NSAMP / 64), dim3(256), 0, stream>>>(hap, Tp, W2t, b2, outp);
}

// Round 8
// 263.436 us; speedup vs baseline: 1.1664x; 1.1664x over previous
//
#include <hip/hip_runtime.h>
#include <math.h>

typedef __attribute__((ext_vector_type(8))) short  short8;   // 8 bf16 (4 VGPRs) - MFMA A/B frag
typedef __attribute__((ext_vector_type(4))) float  floatx4;  // MFMA C/D frag
typedef __attribute__((ext_vector_type(2))) float  float2v;  // packed pair (v_pk_add_f32)
typedef __attribute__((ext_vector_type(4))) unsigned int uintx4; // 16B vector load

#define NLOCI 8
#define VOCAB 512
#define DDIM  256
#define HID   512
#define NSAMP (8192 * 16)

__device__ __forceinline__ float bitsf(unsigned int u) {
    union { unsigned int u; float f; } c; c.u = u; return c.f;
}
__device__ __forceinline__ unsigned short f2bf(float f) {  // RNE (used in prep, cold path)
    union { float f; unsigned int u; } c; c.f = f;
    unsigned int u = c.u;
    return (unsigned short)((u + 0x7FFFu + ((u >> 16) & 1u)) >> 16);
}
__device__ __forceinline__ unsigned short f2bf_fast(float f) {  // round-half-up, 2 ops
    union { float f; unsigned int u; } c; c.f = f;
    return (unsigned short)((c.u + 0x8000u) >> 16);
}
// tanh-form GELU via exp2+rcp; |diff vs erf-GELU| ~3e-4 << threshold.
__device__ __forceinline__ float gelu_fast(float x) {
    float t = x * x;
    float y = x * __builtin_fmaf(0.035677408f, t, 0.79788456f);
    float e = __builtin_amdgcn_exp2f(y * 2.8853901f);
    float r = __builtin_amdgcn_rcpf(e + 1.0f);
    return x - x * r;
}
// async 16B/lane global->LDS DMA (lane i lands at lds_base + i*16)
__device__ __forceinline__ void async_copy16(const void* g, void* l) {
    __builtin_amdgcn_global_load_lds(
        (const __attribute__((address_space(1))) unsigned int*)g,
        (__attribute__((address_space(3))) unsigned int*)l, 16, 0, 0);
}

// sum 8 loci (packed bf16 pairs) -> GELU -> bf16
__device__ __forceinline__ short8 sum_gelu(const uintx4* g) {
    short8 afrag;
#pragma unroll
    for (int j = 0; j < 4; ++j) {
        float2v u0 = (float2v){bitsf(g[0][j] << 16), bitsf(g[0][j] & 0xFFFF0000u)};
        float2v u1 = (float2v){bitsf(g[1][j] << 16), bitsf(g[1][j] & 0xFFFF0000u)};
        float2v u2 = (float2v){bitsf(g[2][j] << 16), bitsf(g[2][j] & 0xFFFF0000u)};
        float2v u3 = (float2v){bitsf(g[3][j] << 16), bitsf(g[3][j] & 0xFFFF0000u)};
        float2v u4 = (float2v){bitsf(g[4][j] << 16), bitsf(g[4][j] & 0xFFFF0000u)};
        float2v u5 = (float2v){bitsf(g[5][j] << 16), bitsf(g[5][j] & 0xFFFF0000u)};
        float2v u6 = (float2v){bitsf(g[6][j] << 16), bitsf(g[6][j] & 0xFFFF0000u)};
        float2v u7 = (float2v){bitsf(g[7][j] << 16), bitsf(g[7][j] & 0xFFFF0000u)};
        float2v sj = ((u0 + u1) + (u2 + u3)) + ((u4 + u5) + (u6 + u7));
        afrag[2 * j]     = (short)f2bf_fast(gelu_fast(sj[0]));
        afrag[2 * j + 1] = (short)f2bf_fast(gelu_fast(sj[1]));
    }
    return afrag;
}

// ---------------------------------------------------------------------------
// Kernel 1 (merged): blocks [0,512): Tp[l] = tables[l] @ W1-slice, bf16,
// b1 folded into locus 0.  blocks [512,544): W2 transpose+cvt -> W2t.
// XOR-swizzled LDS tiles (32 chunks of 16B per row):
//   element (row, k) lives at row*256 + ((k>>3) ^ (row&31))*8 + (k&7)  [shorts]
// ---------------------------------------------------------------------------
__global__ __launch_bounds__(256) void k_prep(
    const float* __restrict__ tables,   // [8][512][256] f32
    const float* __restrict__ W1,       // [2048][512] f32
    const float* __restrict__ b1,       // [512] f32
    const float* __restrict__ W2,       // [512][256] f32
    unsigned short* __restrict__ Tp,    // [8][512][512] bf16
    unsigned short* __restrict__ W2t)   // [256][512] bf16
{
    __shared__ unsigned short a_lds[64 * 256];   // 32 KB, swizzled
    __shared__ unsigned short bt_lds[64 * 256];  // 32 KB, swizzled (bt[n][k])

    const int t = threadIdx.x;

    if (blockIdx.x >= 512) {
        // ---- W2 transpose+cvt: out[c][r] = bf16(in[r][c]), in [512][256] f32
        const int bid = blockIdx.x - 512;
        const int r0 = (bid & 7) * 64;   // over HID=512 rows
        const int c0 = (bid >> 3) * 64;  // over DDIM=256 cols
        float* tile = (float*)a_lds;     // 64*65*4 = 16.6 KB <= 32 KB
#pragma unroll
        for (int i = 0; i < 16; ++i) {
            int flat = i * 256 + t;
            int rr = flat >> 6, cc = flat & 63;
            tile[rr * 65 + cc] = W2[(r0 + rr) * DDIM + c0 + cc];
        }
        __syncthreads();
#pragma unroll
        for (int i = 0; i < 8; ++i) {
            int flat = i * 256 + t;
            int cc = flat >> 5, rp = (flat & 31) * 2;
            ushort2 v;
            v.x = f2bf(tile[rp * 65 + cc]);
            v.y = f2bf(tile[(rp + 1) * 65 + cc]);
            *(ushort2*)(W2t + (c0 + cc) * HID + r0 + rp) = v;
        }
        return;
    }

    const int l  = blockIdx.x >> 6;
    const int v0 = ((blockIdx.x >> 3) & 7) * 64;
    const int n0 = (blockIdx.x & 7) * 64;

    // ---- stage A (tables tile): float4 coalesced loads, conflict-free writes
    {
        const float* asrc = tables + (l * 512 + v0) * 256;
#pragma unroll
        for (int i = 0; i < 16; ++i) {
            int flat = i * 1024 + t * 4;
            int row = flat >> 8, k = flat & 255;
            float4 v = *(const float4*)(asrc + flat);
            ushort4 pk4;
            pk4.x = f2bf(v.x); pk4.y = f2bf(v.y); pk4.z = f2bf(v.z); pk4.w = f2bf(v.w);
            int chunkX = (k >> 3) ^ (row & 31);
            *(ushort4*)(a_lds + row * 256 + chunkX * 8 + (k & 7)) = pk4;
        }
    }
    // ---- stage B^T: bt[n][k] = bf16(W1[l*256+k][n0+n])
    {
        const int n = t & 63;
        const int kq = (t >> 6) * 64;
        const float* bsrc = W1 + (l * 256) * 512 + n0 + n;
#pragma unroll
        for (int i = 0; i < 8; ++i) {
            int k0 = kq + i * 8;
            short8 pk8;
#pragma unroll
            for (int j = 0; j < 8; ++j)
                pk8[j] = (short)f2bf(bsrc[(k0 + j) * 512]);
            int chunkX = (k0 >> 3) ^ (n & 31);
            *(short8*)(bt_lds + n * 256 + chunkX * 8) = pk8;
        }
    }
    __syncthreads();

    const int wave = t >> 6, lane = t & 63;
    const int p = lane & 15, q = lane >> 4;
    const int arow = wave * 16 + p;

    floatx4 acc[4];
#pragma unroll
    for (int nt = 0; nt < 4; ++nt) acc[nt] = (floatx4){0.f, 0.f, 0.f, 0.f};

#pragma unroll
    for (int kc = 0; kc < 8; ++kc) {
        int cq = kc * 4 + q;
        short8 afrag = *(const short8*)(a_lds + arow * 256 + (cq ^ (arow & 31)) * 8);
#pragma unroll
        for (int nt = 0; nt < 4; ++nt) {
            int brow = nt * 16 + p;
            short8 bfrag = *(const short8*)(bt_lds + brow * 256 + (cq ^ (brow & 31)) * 8);
            acc[nt] = __builtin_amdgcn_mfma_f32_16x16x32_bf16(afrag, bfrag, acc[nt], 0, 0, 0);
        }
    }

    // D: row(M=vocab) = q*4 + r, col(N) = nt*16 + p; fold b1 at l==0
#pragma unroll
    for (int nt = 0; nt < 4; ++nt) {
        int col = n0 + nt * 16 + p;
        float badd = (l == 0) ? b1[col] : 0.0f;
#pragma unroll
        for (int r = 0; r < 4; ++r) {
            int row = v0 + wave * 16 + q * 4 + r;
            Tp[(l * 512 + row) * 512 + col] = f2bf(acc[nt][r] + badd);
        }
    }
}

// ---------------------------------------------------------------------------
// Kernel 2a: k_gather — wave = one sample, lane = one 16B k-chunk.
// The 8 Tp row reads are PERFECTLY COALESCED (64 lanes x 16B = the full 1KB
// row) — no divergence, no per-lane gather buffers, no barriers, no MFMA.
// Tiny register footprint -> natural full occupancy; 8 independent loads per
// wave x ~32 waves/CU = deep MLP. Writes H = gelu(sum_l Tp[l][tok_l]) as
// bf16 [NSAMP][512], stored INSIDE the output buffer (H row m occupies
// exactly out row m's bytes; k_gemm reads its own rows before overwriting).
// ---------------------------------------------------------------------------
__global__ __launch_bounds__(256) void k_gather(
    const int* __restrict__ hap,              // [131072][8] int32
    const unsigned short* __restrict__ Tp,    // [8][512][512] bf16 (b1 folded)
    unsigned short* __restrict__ H)           // [131072][512] bf16 (= out buffer)
{
    const int wid  = (int)((blockIdx.x * 256 + threadIdx.x) >> 6);  // sample
    const int lane = threadIdx.x & 63;
    const char* Tpc = (const char*)Tp;
    const int* hp = hap + wid * 8;

    uintx4 g[8];
#pragma unroll
    for (int l = 0; l < 8; ++l) {
        unsigned tok = ((unsigned)hp[l]) & 511u;
        g[l] = *(const uintx4*)(Tpc + (unsigned)l * 524288u + tok * 1024u
                                + (unsigned)(lane * 16));
    }
    short8 hv = sum_gelu(g);
    *(short8*)(H + wid * 512 + lane * 8) = hv;
}

// ---------------------------------------------------------------------------
// Kernel 2b: k_gemm — out = H @ W2t^T + b2 (M=131072, N=256, K=512).
// Pure streaming GEMM: A(H) and B(W2t) both staged via global_load_lds with
// the r1 measured-zero-conflict XOR layout (slot j at row r holds chunk
// j^(r&7); DMA source pre-swizzled with the same involution; read slot
// (s*4+q)^(p&7)). No gather buffers -> acc[16] AGPR + ~40 arch regs fits
// (256,4); LDS 40KB x 4 blocks = 160KB exactly. H is L3-warm (just written).
// Alias note: H and out are the SAME buffer; block b reads only rows
// [64b, 64b+64) across all 8 k-tiles, then its epilogue overwrites exactly
// those rows — all reads precede all writes per wave, blocks disjoint.
// ---------------------------------------------------------------------------
__global__ __launch_bounds__(256, 4) void k_gemm(
    const unsigned short* H,                  // [131072][512] bf16 (aliases out)
    const unsigned short* __restrict__ W2t,   // [256][512] bf16
    const float* __restrict__ b2,             // [256] f32
    float* out)                               // [131072][256] f32
{
    __shared__ unsigned short b_lds[256 * 64];  // 32 KB [n][64k-tile] swizzled
    __shared__ unsigned short a_lds[64 * 64];   // 8 KB  [m][64k-tile] swizzled

    const int t = threadIdx.x;
    const int wave = t >> 6, lane = t & 63;
    const int p = lane & 15, q = lane >> 4;
    const int m_blk = blockIdx.x * 64;

    // DMA lane mapping (both A and B): dest row r = base + (lane>>3),
    // dest slot j = lane&7; source chunk = j ^ (r&7) = jx (r&7 == drow&7).
    const int drow = lane >> 3;
    const int jx   = (lane & 7) ^ (drow & 7);
    const unsigned short* bsrc = W2t + (wave * 64 + drow) * 512 + jx * 8;
    const unsigned short* asrc = H + (m_blk + wave * 16 + drow) * 512 + jx * 8;
    const int p7 = p & 7;

    floatx4 acc[16];
#pragma unroll
    for (int nt = 0; nt < 16; ++nt) acc[nt] = (floatx4){0.f, 0.f, 0.f, 0.f};

    for (int kb = 0; kb < 8; ++kb) {
        // all waves done reading the previous tile
        asm volatile("s_waitcnt lgkmcnt(0)" ::: "memory");
        __builtin_amdgcn_s_barrier();
        __builtin_amdgcn_sched_barrier(0);
        // B: each wave stages 64 rows (8 instr); A: its own 16 rows (2 instr)
#pragma unroll
        for (int i = 0; i < 8; ++i)
            async_copy16(bsrc + kb * 64 + i * 8 * 512,
                         b_lds + (wave * 64 + i * 8) * 64);
#pragma unroll
        for (int i = 0; i < 2; ++i)
            async_copy16(asrc + kb * 64 + i * 8 * 512,
                         a_lds + (wave * 16 + i * 8) * 64);
        asm volatile("s_waitcnt vmcnt(0)" ::: "memory");
        __builtin_amdgcn_s_barrier();
        __builtin_amdgcn_sched_barrier(0);

#pragma unroll
        for (int s = 0; s < 2; ++s) {
            const int slot = (s * 4 + q) ^ p7;
            short8 afrag = *(const short8*)(a_lds + (wave * 16 + p) * 64 + slot * 8);
            const unsigned short* bb = b_lds + p * 64 + slot * 8;
            __builtin_amdgcn_s_setprio(1);
#pragma unroll
            for (int nt = 0; nt < 16; ++nt) {
                short8 bfrag = *(const short8*)(bb + nt * 1024);
                acc[nt] = __builtin_amdgcn_mfma_f32_16x16x32_bf16(afrag, bfrag, acc[nt], 0, 0, 0);
            }
            __builtin_amdgcn_s_setprio(0);
        }
    }

    // epilogue: D row(M=sample) = q*4+r, col(N) = nt*16+p; add b2, NT store f32
#pragma unroll
    for (int nt = 0; nt < 16; ++nt) {
        int n = nt * 16 + p;
        float b2v = b2[n];
#pragma unroll
        for (int r = 0; r < 4; ++r) {
            int m = m_blk + wave * 16 + q * 4 + r;
            __builtin_nontemporal_store(acc[nt][r] + b2v, out + m * 256 + n);
        }
    }
}

// ---------------------------------------------------------------------------
extern "C" void kernel_launch(void* const* d_in, const int* in_sizes, int n_in,
                              void* d_out, int out_size, void* d_ws, size_t ws_size,
                              hipStream_t stream) {
    const int*   hap    = (const int*)d_in[0];
    const float* tables = (const float*)d_in[1];
    const float* W1     = (const float*)d_in[2];
    const float* b1     = (const float*)d_in[3];
    const float* W2     = (const float*)d_in[4];
    const float* b2     = (const float*)d_in[5];
    float*       outp   = (float*)d_out;

    unsigned short* Tp  = (unsigned short*)d_ws;                        // 4 MB bf16
    unsigned short* W2t = (unsigned short*)d_ws + NLOCI * VOCAB * HID;  // 256 KB
    unsigned short* Hbf = (unsigned short*)d_out;                       // H aliases out

    k_prep<<<dim3(544), dim3(256), 0, stream>>>(tables, W1, b1, W2, Tp, W2t);
    k_gather<<<dim3(NSAMP * 64 / 256), dim3(256), 0, stream>>>(hap, Tp, Hbf);
    k_gemm<<<dim3(NSAMP / 64), dim3(256), 0, stream>>>(Hbf, W2t, b2, outp);
}

// Round 9
// 262.814 us; speedup vs baseline: 1.1692x; 1.0024x over previous
//
#include <hip/hip_runtime.h>
#include <math.h>

typedef __attribute__((ext_vector_type(8))) short  short8;   // 8 bf16 (4 VGPRs) - MFMA A/B frag
typedef __attribute__((ext_vector_type(4))) float  floatx4;  // MFMA C/D frag
typedef __attribute__((ext_vector_type(2))) float  float2v;  // packed pair (v_pk_add_f32)
typedef __attribute__((ext_vector_type(4))) unsigned int uintx4; // 16B vector load

#define NLOCI 8
#define VOCAB 512
#define DDIM  256
#define HID   512
#define NSAMP (8192 * 16)

__device__ __forceinline__ float bitsf(unsigned int u) {
    union { unsigned int u; float f; } c; c.u = u; return c.f;
}
__device__ __forceinline__ unsigned short f2bf(float f) {  // RNE (used in prep, cold path)
    union { float f; unsigned int u; } c; c.f = f;
    unsigned int u = c.u;
    return (unsigned short)((u + 0x7FFFu + ((u >> 16) & 1u)) >> 16);
}
__device__ __forceinline__ unsigned short f2bf_fast(float f) {  // round-half-up, 2 ops
    union { float f; unsigned int u; } c; c.f = f;
    return (unsigned short)((c.u + 0x8000u) >> 16);
}
// tanh-form GELU via exp2+rcp; |diff vs erf-GELU| ~3e-4 << threshold.
__device__ __forceinline__ float gelu_fast(float x) {
    float t = x * x;
    float y = x * __builtin_fmaf(0.035677408f, t, 0.79788456f);
    float e = __builtin_amdgcn_exp2f(y * 2.8853901f);
    float r = __builtin_amdgcn_rcpf(e + 1.0f);
    return x - x * r;
}
// async 16B/lane global->LDS DMA (lane i lands at lds_base + i*16)
__device__ __forceinline__ void async_copy16(const void* g, void* l) {
    __builtin_amdgcn_global_load_lds(
        (const __attribute__((address_space(1))) unsigned int*)g,
        (__attribute__((address_space(3))) unsigned int*)l, 16, 0, 0);
}

// sum 8 loci (packed bf16 pairs) -> GELU -> bf16
__device__ __forceinline__ short8 sum_gelu(const uintx4* g) {
    short8 afrag;
#pragma unroll
    for (int j = 0; j < 4; ++j) {
        float2v u0 = (float2v){bitsf(g[0][j] << 16), bitsf(g[0][j] & 0xFFFF0000u)};
        float2v u1 = (float2v){bitsf(g[1][j] << 16), bitsf(g[1][j] & 0xFFFF0000u)};
        float2v u2 = (float2v){bitsf(g[2][j] << 16), bitsf(g[2][j] & 0xFFFF0000u)};
        float2v u3 = (float2v){bitsf(g[3][j] << 16), bitsf(g[3][j] & 0xFFFF0000u)};
        float2v u4 = (float2v){bitsf(g[4][j] << 16), bitsf(g[4][j] & 0xFFFF0000u)};
        float2v u5 = (float2v){bitsf(g[5][j] << 16), bitsf(g[5][j] & 0xFFFF0000u)};
        float2v u6 = (float2v){bitsf(g[6][j] << 16), bitsf(g[6][j] & 0xFFFF0000u)};
        float2v u7 = (float2v){bitsf(g[7][j] << 16), bitsf(g[7][j] & 0xFFFF0000u)};
        float2v sj = ((u0 + u1) + (u2 + u3)) + ((u4 + u5) + (u6 + u7));
        afrag[2 * j]     = (short)f2bf_fast(gelu_fast(sj[0]));
        afrag[2 * j + 1] = (short)f2bf_fast(gelu_fast(sj[1]));
    }
    return afrag;
}

// ---------------------------------------------------------------------------
// Kernel 1 (merged): blocks [0,512): Tp[l] = tables[l] @ W1-slice, bf16,
// b1 folded into locus 0.  blocks [512,544): W2 transpose+cvt -> W2t.
// XOR-swizzled LDS tiles (32 chunks of 16B per row):
//   element (row, k) lives at row*256 + ((k>>3) ^ (row&31))*8 + (k&7)  [shorts]
// ---------------------------------------------------------------------------
__global__ __launch_bounds__(256) void k_prep(
    const float* __restrict__ tables,   // [8][512][256] f32
    const float* __restrict__ W1,       // [2048][512] f32
    const float* __restrict__ b1,       // [512] f32
    const float* __restrict__ W2,       // [512][256] f32
    unsigned short* __restrict__ Tp,    // [8][512][512] bf16
    unsigned short* __restrict__ W2t)   // [256][512] bf16
{
    __shared__ unsigned short a_lds[64 * 256];   // 32 KB, swizzled
    __shared__ unsigned short bt_lds[64 * 256];  // 32 KB, swizzled (bt[n][k])

    const int t = threadIdx.x;

    if (blockIdx.x >= 512) {
        // ---- W2 transpose+cvt: out[c][r] = bf16(in[r][c]), in [512][256] f32
        const int bid = blockIdx.x - 512;
        const int r0 = (bid & 7) * 64;   // over HID=512 rows
        const int c0 = (bid >> 3) * 64;  // over DDIM=256 cols
        float* tile = (float*)a_lds;     // 64*65*4 = 16.6 KB <= 32 KB
#pragma unroll
        for (int i = 0; i < 16; ++i) {
            int flat = i * 256 + t;
            int rr = flat >> 6, cc = flat & 63;
            tile[rr * 65 + cc] = W2[(r0 + rr) * DDIM + c0 + cc];
        }
        __syncthreads();
#pragma unroll
        for (int i = 0; i < 8; ++i) {
            int flat = i * 256 + t;
            int cc = flat >> 5, rp = (flat & 31) * 2;
            ushort2 v;
            v.x = f2bf(tile[rp * 65 + cc]);
            v.y = f2bf(tile[(rp + 1) * 65 + cc]);
            *(ushort2*)(W2t + (c0 + cc) * HID + r0 + rp) = v;
        }
        return;
    }

    const int l  = blockIdx.x >> 6;
    const int v0 = ((blockIdx.x >> 3) & 7) * 64;
    const int n0 = (blockIdx.x & 7) * 64;

    // ---- stage A (tables tile): float4 coalesced loads, conflict-free writes
    {
        const float* asrc = tables + (l * 512 + v0) * 256;
#pragma unroll
        for (int i = 0; i < 16; ++i) {
            int flat = i * 1024 + t * 4;
            int row = flat >> 8, k = flat & 255;
            float4 v = *(const float4*)(asrc + flat);
            ushort4 pk4;
            pk4.x = f2bf(v.x); pk4.y = f2bf(v.y); pk4.z = f2bf(v.z); pk4.w = f2bf(v.w);
            int chunkX = (k >> 3) ^ (row & 31);
            *(ushort4*)(a_lds + row * 256 + chunkX * 8 + (k & 7)) = pk4;
        }
    }
    // ---- stage B^T: bt[n][k] = bf16(W1[l*256+k][n0+n])
    {
        const int n = t & 63;
        const int kq = (t >> 6) * 64;
        const float* bsrc = W1 + (l * 256) * 512 + n0 + n;
#pragma unroll
        for (int i = 0; i < 8; ++i) {
            int k0 = kq + i * 8;
            short8 pk8;
#pragma unroll
            for (int j = 0; j < 8; ++j)
                pk8[j] = (short)f2bf(bsrc[(k0 + j) * 512]);
            int chunkX = (k0 >> 3) ^ (n & 31);
            *(short8*)(bt_lds + n * 256 + chunkX * 8) = pk8;
        }
    }
    __syncthreads();

    const int wave = t >> 6, lane = t & 63;
    const int p = lane & 15, q = lane >> 4;
    const int arow = wave * 16 + p;

    floatx4 acc[4];
#pragma unroll
    for (int nt = 0; nt < 4; ++nt) acc[nt] = (floatx4){0.f, 0.f, 0.f, 0.f};

#pragma unroll
    for (int kc = 0; kc < 8; ++kc) {
        int cq = kc * 4 + q;
        short8 afrag = *(const short8*)(a_lds + arow * 256 + (cq ^ (arow & 31)) * 8);
#pragma unroll
        for (int nt = 0; nt < 4; ++nt) {
            int brow = nt * 16 + p;
            short8 bfrag = *(const short8*)(bt_lds + brow * 256 + (cq ^ (brow & 31)) * 8);
            acc[nt] = __builtin_amdgcn_mfma_f32_16x16x32_bf16(afrag, bfrag, acc[nt], 0, 0, 0);
        }
    }

    // D: row(M=vocab) = q*4 + r, col(N) = nt*16 + p; fold b1 at l==0
#pragma unroll
    for (int nt = 0; nt < 4; ++nt) {
        int col = n0 + nt * 16 + p;
        float badd = (l == 0) ? b1[col] : 0.0f;
#pragma unroll
        for (int r = 0; r < 4; ++r) {
            int row = v0 + wave * 16 + q * 4 + r;
            Tp[(l * 512 + row) * 512 + col] = f2bf(acc[nt][r] + badd);
        }
    }
}

// ---------------------------------------------------------------------------
// Kernel 2a: k_gather — wave = one sample, lane = one 16B k-chunk.
// The 8 Tp row reads are PERFECTLY COALESCED (64 lanes x 16B = the full 1KB
// row). Writes H = gelu(sum_l Tp[l][tok_l]) as bf16 [NSAMP][512], stored
// inside the output buffer (H row m = out row m's bytes; k_gemm reads its
// own rows before overwriting them).
// ---------------------------------------------------------------------------
__global__ __launch_bounds__(256) void k_gather(
    const int* __restrict__ hap,              // [131072][8] int32
    const unsigned short* __restrict__ Tp,    // [8][512][512] bf16 (b1 folded)
    unsigned short* __restrict__ H)           // [131072][512] bf16 (= out buffer)
{
    const int wid  = (int)((blockIdx.x * 256 + threadIdx.x) >> 6);  // sample
    const int lane = threadIdx.x & 63;
    const char* Tpc = (const char*)Tp;
    const int* hp = hap + wid * 8;

    uintx4 g[8];
#pragma unroll
    for (int l = 0; l < 8; ++l) {
        unsigned tok = ((unsigned)hp[l]) & 511u;
        g[l] = *(const uintx4*)(Tpc + (unsigned)l * 524288u + tok * 1024u
                                + (unsigned)(lane * 16));
    }
    short8 hv = sum_gelu(g);
    *(short8*)(H + wid * 512 + lane * 8) = hv;
}

// ---------------------------------------------------------------------------
// Kernel 2b: k_gemm — out = H @ W2t^T + b2 (M=131072, N=256, K=512).
// ROUND 9 CHANGE: 2-phase double-buffered pipeline with COUNTED vmcnt (T3/T4
// minimum recipe). The r8 version drained vmcnt(0) per tile -> each wave ate
// the full ~600-900cy H-read latency 8x. Now tile kb+1's 10 DMAs are issued
// BEFORE computing tile kb and wait vmcnt(10) (counted: next tile's loads
// stay in flight across both barriers). LDS 80 KB -> 2 blocks/CU;
// __launch_bounds__(256,2) = 256-VGPR budget -> spill structurally excluded
// (the r3/r4/r7 failure mode). Same measured-zero-conflict XOR layout.
// Alias note: H and out are the SAME buffer; block b reads only rows
// [64b,64b+64) (all DMA reads precede epilogue stores; blocks disjoint).
// ---------------------------------------------------------------------------
__global__ __launch_bounds__(256, 2) void k_gemm(
    const unsigned short* H,                  // [131072][512] bf16 (aliases out)
    const unsigned short* __restrict__ W2t,   // [256][512] bf16
    const float* __restrict__ b2,             // [256] f32
    float* out)                               // [131072][256] f32
{
    __shared__ unsigned short b_lds[2][256 * 64];  // 64 KB, swizzled dbuf
    __shared__ unsigned short a_lds[2][64 * 64];   // 16 KB, swizzled dbuf

    const int t = threadIdx.x;
    const int wave = t >> 6, lane = t & 63;
    const int p = lane & 15, q = lane >> 4;
    const int m_blk = blockIdx.x * 64;

    // DMA lane mapping (both A and B): dest row r = base + (lane>>3),
    // dest slot j = lane&7; source chunk = j ^ (r&7) = jx (r&7 == drow&7).
    const int drow = lane >> 3;
    const int jx   = (lane & 7) ^ (drow & 7);
    const unsigned short* bsrc = W2t + (wave * 64 + drow) * 512 + jx * 8;
    const unsigned short* asrc = H + (m_blk + wave * 16 + drow) * 512 + jx * 8;
    const int p7 = p & 7;

    floatx4 acc[16];
#pragma unroll
    for (int nt = 0; nt < 16; ++nt) acc[nt] = (floatx4){0.f, 0.f, 0.f, 0.f};

    auto stage = [&](int buf, int kb) {
#pragma unroll
        for (int i = 0; i < 8; ++i)
            async_copy16(bsrc + kb * 64 + i * 8 * 512,
                         &b_lds[buf][(wave * 64 + i * 8) * 64]);
#pragma unroll
        for (int i = 0; i < 2; ++i)
            async_copy16(asrc + kb * 64 + i * 8 * 512,
                         &a_lds[buf][(wave * 16 + i * 8) * 64]);
    };

    // prologue: stage tile 0 into buf 0
    stage(0, 0);
    __builtin_amdgcn_sched_barrier(0);

#pragma unroll
    for (int kb = 0; kb < 8; ++kb) {
        const int cur = kb & 1;
        // issue NEXT tile's 10 DMAs before computing current (latency hides
        // under this tile's MFMA + the co-resident block)
        if (kb < 7) {
            stage(cur ^ 1, kb + 1);
            __builtin_amdgcn_sched_barrier(0);
        }
        // counted wait: current tile's 10 (oldest) landed; next tile's 10
        // stay in flight across the barrier
        if (kb < 7) { asm volatile("s_waitcnt vmcnt(10)" ::: "memory"); }
        else        { asm volatile("s_waitcnt vmcnt(0)"  ::: "memory"); }
        __builtin_amdgcn_s_barrier();
        __builtin_amdgcn_sched_barrier(0);

#pragma unroll
        for (int s = 0; s < 2; ++s) {
            const int slot = (s * 4 + q) ^ p7;
            short8 afrag = *(const short8*)(&a_lds[cur][(wave * 16 + p) * 64 + slot * 8]);
            const unsigned short* bb = &b_lds[cur][p * 64 + slot * 8];
            __builtin_amdgcn_s_setprio(1);
#pragma unroll
            for (int nt = 0; nt < 16; ++nt) {
                short8 bfrag = *(const short8*)(bb + nt * 1024);
                acc[nt] = __builtin_amdgcn_mfma_f32_16x16x32_bf16(afrag, bfrag, acc[nt], 0, 0, 0);
            }
            __builtin_amdgcn_s_setprio(0);
        }

        // all waves done reading buf cur before it is re-staged at kb+2
        asm volatile("s_waitcnt lgkmcnt(0)" ::: "memory");
        __builtin_amdgcn_s_barrier();
        __builtin_amdgcn_sched_barrier(0);
    }

    // epilogue: D row(M=sample) = q*4+r, col(N) = nt*16+p; add b2, NT store f32
#pragma unroll
    for (int nt = 0; nt < 16; ++nt) {
        int n = nt * 16 + p;
        float b2v = b2[n];
#pragma unroll
        for (int r = 0; r < 4; ++r) {
            int m = m_blk + wave * 16 + q * 4 + r;
            __builtin_nontemporal_store(acc[nt][r] + b2v, out + m * 256 + n);
        }
    }
}

// ---------------------------------------------------------------------------
extern "C" void kernel_launch(void* const* d_in, const int* in_sizes, int n_in,
                              void* d_out, int out_size, void* d_ws, size_t ws_size,
                              hipStream_t stream) {
    const int*   hap    = (const int*)d_in[0];
    const float* tables = (const float*)d_in[1];
    const float* W1     = (const float*)d_in[2];
    const float* b1     = (const float*)d_in[3];
    const float* W2     = (const float*)d_in[4];
    const float* b2     = (const float*)d_in[5];
    float*       outp   = (float*)d_out;

    unsigned short* Tp  = (unsigned short*)d_ws;                        // 4 MB bf16
    unsigned short* W2t = (unsigned short*)d_ws + NLOCI * VOCAB * HID;  // 256 KB
    unsigned short* Hbf = (unsigned short*)d_out;                       // H aliases out

    k_prep<<<dim3(544), dim3(256), 0, stream>>>(tables, W1, b1, W2, Tp, W2t);
    k_gather<<<dim3(NSAMP * 64 / 256), dim3(256), 0, stream>>>(hap, Tp, Hbf);
    k_gemm<<<dim3(NSAMP / 64), dim3(256), 0, stream>>>(Hbf, W2t, b2, outp);
}